// Round 20
// baseline (966.597 us; speedup 1.0000x reference)
//
#include <hip/hip_runtime.h>

// y[m][n] = sum_k x[m][k] * (w[n][k]*scale[n]) + bias[n]
// M=8192, N=11008, K=4096. fp32 in/out, bf16 MFMA compute.
//
// R20 = R19 skeleton (verified: 852us GEMM, 0 conflicts, no spill) with
// ONE change: MFMA shape 16x16x32 -> 32x32x16 (2382 vs 2075 TF ubench;
// half the MFMA instructions -> more issue slots). Identical barriers,
// stage slots, vmcnt/lgkm ledger, LDS layout, swizzle, staging.
// A-operand layout derived from validated 16x16 pattern: lane l holds
// A[row=l&31][k=(l>>5)*8+j]; B symmetric on B^T. C/D layout (m74/m101):
// col=lane&31, row=(reg&3)+8*(reg>>2)+4*(lane>>5).
#define M_DIM 8192
#define N_DIM 11008
#define K_DIM 4096
#define BM 256
#define BN 256
#define BK 64
#define NT (K_DIM / BK)   // 64 K-tiles
#define NIT (NT / 2)      // 32 iterations, 2 K-tiles each
#define TM (M_DIM / BM)   // 32
#define TN (N_DIM / BN)   // 43
#define NWG (TM * TN)     // 1376 (divisible by 8)

typedef __attribute__((ext_vector_type(8))) short bf16x8;
typedef __attribute__((ext_vector_type(8))) unsigned short u16x8;
typedef __attribute__((ext_vector_type(16))) float f32x16;

__device__ __forceinline__ unsigned short f2bf(float f) {
  union { float f; unsigned u; } v; v.f = f;
  unsigned r = v.u + 0x7FFFu + ((v.u >> 16) & 1u);  // RNE
  return (unsigned short)(r >> 16);
}

__device__ __forceinline__ void gload_lds16(const unsigned short* g, unsigned short* l) {
  __builtin_amdgcn_global_load_lds(
      (const __attribute__((address_space(1))) void*)g,
      (__attribute__((address_space(3))) void*)l, 16, 0, 0);
}

// Involution swizzle within a 16 KB half-tile (128 rows x 128 B): XOR the
// 16B-unit index (bits 4-6) with row bits 0-2 (bits 7-9). 0 conflicts
// measured (R10/R12/R19); 32-row frag reads also land 2 lanes/bank.
__device__ __forceinline__ int swz(int b) { return b ^ (((b >> 7) & 7) << 4); }

#define BAR() asm volatile("s_barrier" ::: "memory")

// ---- pre-convert kernels (memory-bound) ----
__global__ void cvt_x_kernel(const float* __restrict__ in, unsigned short* __restrict__ o) {
  size_t i = (size_t)blockIdx.x * 256 + threadIdx.x;
  const float4* p = (const float4*)in + i * 2;
  float4 f0 = p[0], f1 = p[1];
  u16x8 v;
  v[0] = f2bf(f0.x); v[1] = f2bf(f0.y); v[2] = f2bf(f0.z); v[3] = f2bf(f0.w);
  v[4] = f2bf(f1.x); v[5] = f2bf(f1.y); v[6] = f2bf(f1.z); v[7] = f2bf(f1.w);
  *((u16x8*)o + i) = v;
}

__global__ void cvt_w_kernel(const float* __restrict__ in, const float* __restrict__ sc,
                             unsigned short* __restrict__ o) {
  size_t i = (size_t)blockIdx.x * 256 + threadIdx.x;
  float s = sc[i >> 9];  // 4096/8 = 512 packs per row
  const float4* p = (const float4*)in + i * 2;
  float4 f0 = p[0], f1 = p[1];
  u16x8 v;
  v[0] = f2bf(f0.x * s); v[1] = f2bf(f0.y * s); v[2] = f2bf(f0.z * s); v[3] = f2bf(f0.w * s);
  v[4] = f2bf(f1.x * s); v[5] = f2bf(f1.y * s); v[6] = f2bf(f1.z * s); v[7] = f2bf(f1.w * s);
  *((u16x8*)o + i) = v;
}

// ---- GEMM ----
__launch_bounds__(512, 2)
__global__ void gemm_kernel(const unsigned short* __restrict__ xb,
                            const unsigned short* __restrict__ wb,
                            const float* __restrict__ bias,
                            float* __restrict__ out) {
  // [dbuf][half]: half-tile = 128 rows x 64 k bf16 = 16 KB. Total 128 KB.
  __shared__ unsigned short As[2][2][8192];
  __shared__ unsigned short Bs[2][2][8192];

  const int tid = threadIdx.x;
  const int lane = tid & 63;
  const int wave = tid >> 6;
  const int wr = wave >> 2;   // 0..1 -> 128-row half of A (= A half index)
  const int wc = wave & 3;    // 0..3 -> 64-col slice of B (half = wc>>1)

  // T1: XCD-aware swizzle (bijective, NWG%8==0), column-major within chunk.
  int orig = blockIdx.x;
  int wg = (orig & 7) * (NWG / 8) + (orig >> 3);
  int bx = wg / TM;           // N tile 0..42
  int by = wg % TM;           // M tile 0..31
  const int rowBase = by * BM;
  const int colBase = bx * BN;

  // acc: 4 m-tiles (32) x 2 n-tiles (32) of f32x16 = 128 regs (AGPR).
  f32x16 acc32[4][2] = {};

  const int cl = lane & 31;          // col within 32-tile / A row within tile
  const int kq = (lane >> 5) * 16;   // byte k-offset of the 8-elem sub-frag

  float bias_v[2];
#pragma unroll
  for (int nt = 0; nt < 2; ++nt)
    bias_v[nt] = bias[colBase + wc * 64 + nt * 32 + cl];

  // staging: half-tile = 16 KB = 512 threads x 2 x 16 B. Linear LDS dest,
  // pre-swizzled global source (rule #21: same involution both sides).
  const int L0 = tid * 16, L1 = L0 + 8192;
  const int S0 = swz(L0), S1 = swz(L1);
  const int sr0 = S0 >> 7, sc0_ = (S0 & 127) >> 1;
  const int sr1 = S1 >> 7, sc1_ = (S1 & 127) >> 1;

  auto stageA = [&](int kt, int half) {
    const unsigned short* src =
        xb + (size_t)(rowBase + half * 128) * K_DIM + (size_t)kt * BK;
    unsigned short* dst = &As[kt & 1][half][0];
    gload_lds16(src + (size_t)sr0 * K_DIM + sc0_, dst + (L0 >> 1));
    gload_lds16(src + (size_t)sr1 * K_DIM + sc1_, dst + (L1 >> 1));
  };
  auto stageB = [&](int kt, int half) {
    const unsigned short* src =
        wb + (size_t)(colBase + half * 128) * K_DIM + (size_t)kt * BK;
    unsigned short* dst = &Bs[kt & 1][half][0];
    gload_lds16(src + (size_t)sr0 * K_DIM + sc0_, dst + (L0 >> 1));
    gload_lds16(src + (size_t)sr1 * K_DIM + sc1_, dst + (L1 >> 1));
  };

  bf16x8 aF[8], bLo[4], bHi[4];

  // A frags for row-quadrant qm (64 rows = m-tiles 2qm, 2qm+1), all 4
  // k-steps: 8 x ds_read_b128 (same count/phase as R19).
  auto rdA = [&](int d, int qm) {
    const char* Ab = (const char*)&As[d][wr][0];
#pragma unroll
    for (int mi = 0; mi < 2; ++mi)
#pragma unroll
      for (int ks = 0; ks < 4; ++ks) {
        int b = ((qm * 2 + mi) * 32 + cl) * 128 + ks * 32 + kq;
        aF[mi * 4 + ks] = *(const bf16x8*)(Ab + swz(b));
      }
  };
  // B frags for col-tile qn (32 cols), all 4 k-steps: 4 x ds_read_b128.
  auto rdB = [&](int d, int qn, bf16x8* bf) {
    const char* Bb = (const char*)&Bs[d][wc >> 1][0];
#pragma unroll
    for (int ks = 0; ks < 4; ++ks) {
      int b = ((wc & 1) * 64 + qn * 32 + cl) * 128 + ks * 32 + kq;
      bf[ks] = *(const bf16x8*)(Bb + swz(b));
    }
  };
  auto mma = [&](int qm, int qn, const bf16x8* bf) {
    __builtin_amdgcn_s_setprio(1);
#pragma unroll
    for (int mi = 0; mi < 2; ++mi)
#pragma unroll
      for (int ks = 0; ks < 4; ++ks)
        acc32[qm * 2 + mi][qn] = __builtin_amdgcn_mfma_f32_32x32x16_bf16(
            aF[mi * 4 + ks], bf[ks], acc32[qm * 2 + mi][qn], 0, 0, 0);
    __builtin_amdgcn_s_setprio(0);
  };

  // Skeleton identical to R19 (quadrants (0,0),(0,1),(1,1),(1,0); merged
  // ph3/ph7; early stage slots; lgkm pacing; vmcnt(4) once per K-tile).
  auto iter = [&](int a, bool f) {
    const int b = a + 1;
    // ph1
    rdA(0, 0); rdB(0, 0, bLo);
    stageA(b, 0);
    asm volatile("s_waitcnt lgkmcnt(8)" ::: "memory");
    BAR(); mma(0, 0, bLo); BAR();
    // ph2
    rdB(0, 1, bHi);
    stageA(b, 1);
    BAR();
    mma(0, 1, bHi);
    if (f) stageB(a + 2, 0);
    BAR();
    // ph3' (merged)
    rdA(0, 1);
    if (f) stageB(a + 2, 1);
    BAR();
    mma(1, 1, bHi);
    mma(1, 0, bLo);
    if (f) { asm volatile("s_waitcnt vmcnt(4)" ::: "memory"); }
    else   { asm volatile("s_waitcnt vmcnt(0)" ::: "memory"); }
    BAR();
    // ph5
    rdA(1, 0); rdB(1, 0, bLo);
    if (f) stageA(a + 2, 0);
    asm volatile("s_waitcnt lgkmcnt(8)" ::: "memory");
    BAR(); mma(0, 0, bLo); BAR();
    // ph6
    rdB(1, 1, bHi);
    if (f) stageA(a + 2, 1);
    BAR();
    mma(0, 1, bHi);
    if (f) stageB(a + 3, 0);
    BAR();
    // ph7' (merged)
    rdA(1, 1);
    if (f) stageB(a + 3, 1);
    BAR();
    mma(1, 1, bHi);
    mma(1, 0, bLo);
    if (f) { asm volatile("s_waitcnt vmcnt(4)" ::: "memory"); }
    BAR();
  };

  // prologue: B(0), A(0), B(1) = 12 loads; vmcnt(4) leaves B(1) in flight.
  stageB(0, 0); stageB(0, 1);
  stageA(0, 0); stageA(0, 1);
  stageB(1, 0); stageB(1, 1);
  asm volatile("s_waitcnt vmcnt(4)" ::: "memory");
  BAR();

  for (int it = 0; it < NIT - 1; ++it) iter(2 * it, true);
  iter(NT - 2, false);

  // epilogue: 32x32 C/D layout (m74/m101): col=lane&31,
  // row=(reg&3)+8*(reg>>2)+4*(lane>>5).
  const int rb = 4 * (lane >> 5);
#pragma unroll
  for (int mt = 0; mt < 4; ++mt) {
#pragma unroll
    for (int nt = 0; nt < 2; ++nt) {
#pragma unroll
      for (int r = 0; r < 16; ++r) {
        size_t row = (size_t)(rowBase + wr * 128 + mt * 32 + (r & 3) + 8 * (r >> 2) + rb);
        out[row * N_DIM + colBase + wc * 64 + nt * 32 + cl] = acc32[mt][nt][r] + bias_v[nt];
      }
    }
  }
}

extern "C" void kernel_launch(void* const* d_in, const int* in_sizes, int n_in,
                              void* d_out, int out_size, void* d_ws, size_t ws_size,
                              hipStream_t stream) {
  const float* x = (const float*)d_in[0];   // [8192][4096]
  const float* w = (const float*)d_in[1];   // [11008][4096]
  const float* sc = (const float*)d_in[2];  // [11008]
  const float* bi = (const float*)d_in[3];  // [11008]
  float* out = (float*)d_out;

  const size_t xe = (size_t)M_DIM * K_DIM;
  const size_t we = (size_t)N_DIM * K_DIM;
  unsigned short* xb = (unsigned short*)d_ws;
  unsigned short* wb = xb + xe;

  cvt_x_kernel<<<(unsigned)(xe / 8 / 256), 256, 0, stream>>>(x, xb);
  cvt_w_kernel<<<(unsigned)(we / 8 / 256), 256, 0, stream>>>(w, sc, wb);
  gemm_kernel<<<NWG, 512, 0, stream>>>(xb, wb, bi, out);
}

// Round 21
// 910.760 us; speedup vs baseline: 1.0613x; 1.0613x over previous
//
#include <hip/hip_runtime.h>

// y[m][n] = sum_k x[m][k] * (w[n][k]*scale[n]) + bias[n]
// M=8192, N=11008, K=4096. fp32 in/out, bf16 MFMA compute.
//
// FINAL = R19 (session best: 911us total, 852us GEMM, absmax 2.0).
// 256x256 tile, 8 waves (2Mx4N), BK=64, 2-dbuf LDS (128 KB), 6 barriers
// per K-tile (merged ph3/ph7), early stage slots, lgkmcnt(8) pacing,
// counted vmcnt(4) once per K-tile (never 0 mid-loop), 16x16x32 bf16
// MFMA (32x32x16 regressed: structural 4-way bank conflict, R20),
// XOR swizzle (0 conflicts), XCD block swizzle (T1), setprio (T5).
#define M_DIM 8192
#define N_DIM 11008
#define K_DIM 4096
#define BM 256
#define BN 256
#define BK 64
#define NT (K_DIM / BK)   // 64 K-tiles
#define NIT (NT / 2)      // 32 iterations, 2 K-tiles each
#define TM (M_DIM / BM)   // 32
#define TN (N_DIM / BN)   // 43
#define NWG (TM * TN)     // 1376 (divisible by 8)

typedef __attribute__((ext_vector_type(8))) short bf16x8;
typedef __attribute__((ext_vector_type(8))) unsigned short u16x8;
typedef __attribute__((ext_vector_type(4))) float f32x4;

__device__ __forceinline__ unsigned short f2bf(float f) {
  union { float f; unsigned u; } v; v.f = f;
  unsigned r = v.u + 0x7FFFu + ((v.u >> 16) & 1u);  // RNE
  return (unsigned short)(r >> 16);
}

__device__ __forceinline__ void gload_lds16(const unsigned short* g, unsigned short* l) {
  __builtin_amdgcn_global_load_lds(
      (const __attribute__((address_space(1))) void*)g,
      (__attribute__((address_space(3))) void*)l, 16, 0, 0);
}

// Involution swizzle within a 16 KB half-tile (128 rows x 128 B): XOR the
// 16B-unit index (bits 4-6) with row bits 0-2 (bits 7-9). 0 conflicts
// measured (R10/R12/R19).
__device__ __forceinline__ int swz(int b) { return b ^ (((b >> 7) & 7) << 4); }

#define BAR() asm volatile("s_barrier" ::: "memory")

// ---- pre-convert kernels (memory-bound) ----
__global__ void cvt_x_kernel(const float* __restrict__ in, unsigned short* __restrict__ o) {
  size_t i = (size_t)blockIdx.x * 256 + threadIdx.x;
  const float4* p = (const float4*)in + i * 2;
  float4 f0 = p[0], f1 = p[1];
  u16x8 v;
  v[0] = f2bf(f0.x); v[1] = f2bf(f0.y); v[2] = f2bf(f0.z); v[3] = f2bf(f0.w);
  v[4] = f2bf(f1.x); v[5] = f2bf(f1.y); v[6] = f2bf(f1.z); v[7] = f2bf(f1.w);
  *((u16x8*)o + i) = v;
}

__global__ void cvt_w_kernel(const float* __restrict__ in, const float* __restrict__ sc,
                             unsigned short* __restrict__ o) {
  size_t i = (size_t)blockIdx.x * 256 + threadIdx.x;
  float s = sc[i >> 9];  // 4096/8 = 512 packs per row
  const float4* p = (const float4*)in + i * 2;
  float4 f0 = p[0], f1 = p[1];
  u16x8 v;
  v[0] = f2bf(f0.x * s); v[1] = f2bf(f0.y * s); v[2] = f2bf(f0.z * s); v[3] = f2bf(f0.w * s);
  v[4] = f2bf(f1.x * s); v[5] = f2bf(f1.y * s); v[6] = f2bf(f1.z * s); v[7] = f2bf(f1.w * s);
  *((u16x8*)o + i) = v;
}

// ---- GEMM ----
__launch_bounds__(512, 2)
__global__ void gemm_kernel(const unsigned short* __restrict__ xb,
                            const unsigned short* __restrict__ wb,
                            const float* __restrict__ bias,
                            float* __restrict__ out) {
  // [dbuf][half]: half-tile = 128 rows x 64 k bf16 = 16 KB. Total 128 KB.
  __shared__ unsigned short As[2][2][8192];
  __shared__ unsigned short Bs[2][2][8192];

  const int tid = threadIdx.x;
  const int lane = tid & 63;
  const int wave = tid >> 6;
  const int wr = wave >> 2;   // 0..1 -> 128-row half of A (= A half index)
  const int wc = wave & 3;    // 0..3 -> 64-col slice of B (half = wc>>1)

  // T1: XCD-aware swizzle (bijective, NWG%8==0), column-major within chunk.
  int orig = blockIdx.x;
  int wg = (orig & 7) * (NWG / 8) + (orig >> 3);
  int bx = wg / TM;           // N tile 0..42
  int by = wg % TM;           // M tile 0..31
  const int rowBase = by * BM;
  const int colBase = bx * BN;

  f32x4 acc[8][4] = {};

  const int fr = lane & 15;
  const int q16 = (lane >> 4) * 16;  // byte col of the 8-k sub-frag

  float bias_v[4];
#pragma unroll
  for (int n = 0; n < 4; ++n)
    bias_v[n] = bias[colBase + wc * 64 + n * 16 + fr];

  // staging: half-tile = 16 KB = 512 threads x 2 x 16 B. Linear LDS dest,
  // pre-swizzled global source (rule #21: same involution both sides).
  const int L0 = tid * 16, L1 = L0 + 8192;
  const int S0 = swz(L0), S1 = swz(L1);
  const int sr0 = S0 >> 7, sc0_ = (S0 & 127) >> 1;
  const int sr1 = S1 >> 7, sc1_ = (S1 & 127) >> 1;

  auto stageA = [&](int kt, int half) {
    const unsigned short* src =
        xb + (size_t)(rowBase + half * 128) * K_DIM + (size_t)kt * BK;
    unsigned short* dst = &As[kt & 1][half][0];
    gload_lds16(src + (size_t)sr0 * K_DIM + sc0_, dst + (L0 >> 1));
    gload_lds16(src + (size_t)sr1 * K_DIM + sc1_, dst + (L1 >> 1));
  };
  auto stageB = [&](int kt, int half) {
    const unsigned short* src =
        wb + (size_t)(colBase + half * 128) * K_DIM + (size_t)kt * BK;
    unsigned short* dst = &Bs[kt & 1][half][0];
    gload_lds16(src + (size_t)sr0 * K_DIM + sc0_, dst + (L0 >> 1));
    gload_lds16(src + (size_t)sr1 * K_DIM + sc1_, dst + (L1 >> 1));
  };

  bf16x8 aF[8], bLo[4], bHi[4];

  auto rdA = [&](int d, int qm) {
    const char* Ab = (const char*)&As[d][wr][0];
#pragma unroll
    for (int mi = 0; mi < 4; ++mi)
#pragma unroll
      for (int ks = 0; ks < 2; ++ks) {
        int b = (qm * 64 + mi * 16 + fr) * 128 + ks * 64 + q16;
        aF[mi * 2 + ks] = *(const bf16x8*)(Ab + swz(b));
      }
  };
  auto rdB = [&](int d, int qn, bf16x8* bf) {
    const char* Bb = (const char*)&Bs[d][wc >> 1][0];
#pragma unroll
    for (int nj = 0; nj < 2; ++nj)
#pragma unroll
      for (int ks = 0; ks < 2; ++ks) {
        int b = ((wc & 1) * 64 + qn * 32 + nj * 16 + fr) * 128 + ks * 64 + q16;
        bf[nj * 2 + ks] = *(const bf16x8*)(Bb + swz(b));
      }
  };
  auto mma = [&](int qm, int qn, const bf16x8* bf) {
    __builtin_amdgcn_s_setprio(1);
#pragma unroll
    for (int mi = 0; mi < 4; ++mi)
#pragma unroll
      for (int nj = 0; nj < 2; ++nj)
#pragma unroll
        for (int ks = 0; ks < 2; ++ks)
          acc[qm * 4 + mi][qn * 2 + nj] = __builtin_amdgcn_mfma_f32_16x16x32_bf16(
              aF[mi * 2 + ks], bf[nj * 2 + ks], acc[qm * 4 + mi][qn * 2 + nj], 0, 0, 0);
    __builtin_amdgcn_s_setprio(0);
  };

  // One iteration = K-tiles a (dbuf0) and b=a+1 (dbuf1). Quadrant order per
  // K-tile: (0,0),(0,1),(1,1),(1,0); ph3+ph4 / ph7+ph8 merged (R12).
  // Stage schedule (each stage >=1 closed barrier after its region's last
  // read; B-h0 last read ph1, B-h1 ph2, A ph3 within each K-tile):
  //   ph1: A(b)h0 [+lgkmcnt(8) pacing]   ph2: A(b)h1, mid: B(a+2)h0
  //   ph3': pre: B(a+2)h1; vmcnt(4)      ph5: A(a+2)h0 [+pacing]
  //   ph6: A(a+2)h1, mid: B(a+3)h0       ph7': pre: B(a+3)h1; vmcnt(4)
  // Ledger: ph3' vmcnt(4) -> outstanding = B(a+2)h0+h1 -> A(b),B(b)
  // certified for ph5-8. ph7' vmcnt(4) -> outstanding = B(a+3) ->
  // A(a+2),B(a+2) certified for next ph1-4. Never 0 mid-loop.
  auto iter = [&](int a, bool f) {
    const int b = a + 1;
    // ph1
    rdA(0, 0); rdB(0, 0, bLo);
    stageA(b, 0);
    asm volatile("s_waitcnt lgkmcnt(8)" ::: "memory");  // pacing (m201)
    BAR(); mma(0, 0, bLo); BAR();
    // ph2
    rdB(0, 1, bHi);
    stageA(b, 1);
    BAR();
    mma(0, 1, bHi);
    if (f) stageB(a + 2, 0);   // mid-cluster: B-h0 last read ph1 (closed)
    BAR();
    // ph3' (merged)
    rdA(0, 1);
    if (f) stageB(a + 2, 1);   // pre-bar: B-h1 last read ph2 (closed)
    BAR();
    mma(1, 1, bHi);
    mma(1, 0, bLo);
    if (f) { asm volatile("s_waitcnt vmcnt(4)" ::: "memory"); }
    else   { asm volatile("s_waitcnt vmcnt(0)" ::: "memory"); }
    BAR();
    // ph5
    rdA(1, 0); rdB(1, 0, bLo);
    if (f) stageA(a + 2, 0);
    asm volatile("s_waitcnt lgkmcnt(8)" ::: "memory");  // pacing
    BAR(); mma(0, 0, bLo); BAR();
    // ph6
    rdB(1, 1, bHi);
    if (f) stageA(a + 2, 1);
    BAR();
    mma(0, 1, bHi);
    if (f) stageB(a + 3, 0);   // mid-cluster
    BAR();
    // ph7' (merged)
    rdA(1, 1);
    if (f) stageB(a + 3, 1);   // pre-bar
    BAR();
    mma(1, 1, bHi);
    mma(1, 0, bLo);
    if (f) { asm volatile("s_waitcnt vmcnt(4)" ::: "memory"); }
    BAR();
  };

  // prologue: B(0), A(0), B(1) = 12 loads; vmcnt(4) leaves B(1) in flight.
  stageB(0, 0); stageB(0, 1);
  stageA(0, 0); stageA(0, 1);
  stageB(1, 0); stageB(1, 1);
  asm volatile("s_waitcnt vmcnt(4)" ::: "memory");
  BAR();

  for (int it = 0; it < NIT - 1; ++it) iter(2 * it, true);
  iter(NT - 2, false);

  // epilogue: C/D layout col=lane&15, row=(lane>>4)*4+reg (m89/m91)
  const int r0 = (lane >> 4) * 4;
#pragma unroll
  for (int m = 0; m < 8; ++m) {
#pragma unroll
    for (int r = 0; r < 4; ++r) {
      size_t row = (size_t)(rowBase + wr * 128 + m * 16 + r0 + r);
      float* po = out + row * N_DIM + colBase + wc * 64 + fr;
#pragma unroll
      for (int n = 0; n < 4; ++n)
        po[n * 16] = acc[m][n][r] + bias_v[n];
    }
  }
}

extern "C" void kernel_launch(void* const* d_in, const int* in_sizes, int n_in,
                              void* d_out, int out_size, void* d_ws, size_t ws_size,
                              hipStream_t stream) {
  const float* x = (const float*)d_in[0];   // [8192][4096]
  const float* w = (const float*)d_in[1];   // [11008][4096]
  const float* sc = (const float*)d_in[2];  // [11008]
  const float* bi = (const float*)d_in[3];  // [11008]
  float* out = (float*)d_out;

  const size_t xe = (size_t)M_DIM * K_DIM;
  const size_t we = (size_t)N_DIM * K_DIM;
  unsigned short* xb = (unsigned short*)d_ws;
  unsigned short* wb = xb + xe;

  cvt_x_kernel<<<(unsigned)(xe / 8 / 256), 256, 0, stream>>>(x, xb);
  cvt_w_kernel<<<(unsigned)(we / 8 / 256), 256, 0, stream>>>(w, sc, wb);
  gemm_kernel<<<NWG, 512, 0, stream>>>(xb, wb, bi, out);
}

// Round 22
// 907.839 us; speedup vs baseline: 1.0647x; 1.0032x over previous
//
#include <hip/hip_runtime.h>

// y[m][n] = sum_k x[m][k] * (w[n][k]*scale[n]) + bias[n]
// M=8192, N=11008, K=4096. fp32 in/out, bf16 MFMA compute.
//
// FINAL (confirmed twice: R19 911.2us, R21 910.8us; GEMM 852-873us,
// MfmaUtil 38-39%, 0 conflicts, no spill, absmax 2.0).
// 256x256 tile, 8 waves (2Mx4N), BK=64, 2-dbuf LDS (128 KB), 6 barriers
// per K-tile (merged ph3/ph7), early stage slots, lgkmcnt(8) pacing,
// counted vmcnt(4) once per K-tile (never 0 mid-loop), 16x16x32 bf16
// MFMA (32x32x16 regressed: structural 4-way bank conflict, R20),
// XOR swizzle (0 conflicts), XCD block swizzle (T1), setprio (T5).
#define M_DIM 8192
#define N_DIM 11008
#define K_DIM 4096
#define BM 256
#define BN 256
#define BK 64
#define NT (K_DIM / BK)   // 64 K-tiles
#define NIT (NT / 2)      // 32 iterations, 2 K-tiles each
#define TM (M_DIM / BM)   // 32
#define TN (N_DIM / BN)   // 43
#define NWG (TM * TN)     // 1376 (divisible by 8)

typedef __attribute__((ext_vector_type(8))) short bf16x8;
typedef __attribute__((ext_vector_type(8))) unsigned short u16x8;
typedef __attribute__((ext_vector_type(4))) float f32x4;

__device__ __forceinline__ unsigned short f2bf(float f) {
  union { float f; unsigned u; } v; v.f = f;
  unsigned r = v.u + 0x7FFFu + ((v.u >> 16) & 1u);  // RNE
  return (unsigned short)(r >> 16);
}

__device__ __forceinline__ void gload_lds16(const unsigned short* g, unsigned short* l) {
  __builtin_amdgcn_global_load_lds(
      (const __attribute__((address_space(1))) void*)g,
      (__attribute__((address_space(3))) void*)l, 16, 0, 0);
}

// Involution swizzle within a 16 KB half-tile (128 rows x 128 B): XOR the
// 16B-unit index (bits 4-6) with row bits 0-2 (bits 7-9). 0 conflicts
// measured (R10/R12/R19/R21).
__device__ __forceinline__ int swz(int b) { return b ^ (((b >> 7) & 7) << 4); }

#define BAR() asm volatile("s_barrier" ::: "memory")

// ---- pre-convert kernels (memory-bound) ----
__global__ void cvt_x_kernel(const float* __restrict__ in, unsigned short* __restrict__ o) {
  size_t i = (size_t)blockIdx.x * 256 + threadIdx.x;
  const float4* p = (const float4*)in + i * 2;
  float4 f0 = p[0], f1 = p[1];
  u16x8 v;
  v[0] = f2bf(f0.x); v[1] = f2bf(f0.y); v[2] = f2bf(f0.z); v[3] = f2bf(f0.w);
  v[4] = f2bf(f1.x); v[5] = f2bf(f1.y); v[6] = f2bf(f1.z); v[7] = f2bf(f1.w);
  *((u16x8*)o + i) = v;
}

__global__ void cvt_w_kernel(const float* __restrict__ in, const float* __restrict__ sc,
                             unsigned short* __restrict__ o) {
  size_t i = (size_t)blockIdx.x * 256 + threadIdx.x;
  float s = sc[i >> 9];  // 4096/8 = 512 packs per row
  const float4* p = (const float4*)in + i * 2;
  float4 f0 = p[0], f1 = p[1];
  u16x8 v;
  v[0] = f2bf(f0.x * s); v[1] = f2bf(f0.y * s); v[2] = f2bf(f0.z * s); v[3] = f2bf(f0.w * s);
  v[4] = f2bf(f1.x * s); v[5] = f2bf(f1.y * s); v[6] = f2bf(f1.z * s); v[7] = f2bf(f1.w * s);
  *((u16x8*)o + i) = v;
}

// ---- GEMM ----
__launch_bounds__(512, 2)
__global__ void gemm_kernel(const unsigned short* __restrict__ xb,
                            const unsigned short* __restrict__ wb,
                            const float* __restrict__ bias,
                            float* __restrict__ out) {
  // [dbuf][half]: half-tile = 128 rows x 64 k bf16 = 16 KB. Total 128 KB.
  __shared__ unsigned short As[2][2][8192];
  __shared__ unsigned short Bs[2][2][8192];

  const int tid = threadIdx.x;
  const int lane = tid & 63;
  const int wave = tid >> 6;
  const int wr = wave >> 2;   // 0..1 -> 128-row half of A (= A half index)
  const int wc = wave & 3;    // 0..3 -> 64-col slice of B (half = wc>>1)

  // T1: XCD-aware swizzle (bijective, NWG%8==0), column-major within chunk.
  int orig = blockIdx.x;
  int wg = (orig & 7) * (NWG / 8) + (orig >> 3);
  int bx = wg / TM;           // N tile 0..42
  int by = wg % TM;           // M tile 0..31
  const int rowBase = by * BM;
  const int colBase = bx * BN;

  f32x4 acc[8][4] = {};

  const int fr = lane & 15;
  const int q16 = (lane >> 4) * 16;  // byte col of the 8-k sub-frag

  float bias_v[4];
#pragma unroll
  for (int n = 0; n < 4; ++n)
    bias_v[n] = bias[colBase + wc * 64 + n * 16 + fr];

  // staging: half-tile = 16 KB = 512 threads x 2 x 16 B. Linear LDS dest,
  // pre-swizzled global source (rule #21: same involution both sides).
  const int L0 = tid * 16, L1 = L0 + 8192;
  const int S0 = swz(L0), S1 = swz(L1);
  const int sr0 = S0 >> 7, sc0_ = (S0 & 127) >> 1;
  const int sr1 = S1 >> 7, sc1_ = (S1 & 127) >> 1;

  auto stageA = [&](int kt, int half) {
    const unsigned short* src =
        xb + (size_t)(rowBase + half * 128) * K_DIM + (size_t)kt * BK;
    unsigned short* dst = &As[kt & 1][half][0];
    gload_lds16(src + (size_t)sr0 * K_DIM + sc0_, dst + (L0 >> 1));
    gload_lds16(src + (size_t)sr1 * K_DIM + sc1_, dst + (L1 >> 1));
  };
  auto stageB = [&](int kt, int half) {
    const unsigned short* src =
        wb + (size_t)(colBase + half * 128) * K_DIM + (size_t)kt * BK;
    unsigned short* dst = &Bs[kt & 1][half][0];
    gload_lds16(src + (size_t)sr0 * K_DIM + sc0_, dst + (L0 >> 1));
    gload_lds16(src + (size_t)sr1 * K_DIM + sc1_, dst + (L1 >> 1));
  };

  bf16x8 aF[8], bLo[4], bHi[4];

  auto rdA = [&](int d, int qm) {
    const char* Ab = (const char*)&As[d][wr][0];
#pragma unroll
    for (int mi = 0; mi < 4; ++mi)
#pragma unroll
      for (int ks = 0; ks < 2; ++ks) {
        int b = (qm * 64 + mi * 16 + fr) * 128 + ks * 64 + q16;
        aF[mi * 2 + ks] = *(const bf16x8*)(Ab + swz(b));
      }
  };
  auto rdB = [&](int d, int qn, bf16x8* bf) {
    const char* Bb = (const char*)&Bs[d][wc >> 1][0];
#pragma unroll
    for (int nj = 0; nj < 2; ++nj)
#pragma unroll
      for (int ks = 0; ks < 2; ++ks) {
        int b = ((wc & 1) * 64 + qn * 32 + nj * 16 + fr) * 128 + ks * 64 + q16;
        bf[nj * 2 + ks] = *(const bf16x8*)(Bb + swz(b));
      }
  };
  auto mma = [&](int qm, int qn, const bf16x8* bf) {
    __builtin_amdgcn_s_setprio(1);
#pragma unroll
    for (int mi = 0; mi < 4; ++mi)
#pragma unroll
      for (int nj = 0; nj < 2; ++nj)
#pragma unroll
        for (int ks = 0; ks < 2; ++ks)
          acc[qm * 4 + mi][qn * 2 + nj] = __builtin_amdgcn_mfma_f32_16x16x32_bf16(
              aF[mi * 2 + ks], bf[nj * 2 + ks], acc[qm * 4 + mi][qn * 2 + nj], 0, 0, 0);
    __builtin_amdgcn_s_setprio(0);
  };

  // One iteration = K-tiles a (dbuf0) and b=a+1 (dbuf1). Quadrant order per
  // K-tile: (0,0),(0,1),(1,1),(1,0); ph3+ph4 / ph7+ph8 merged (R12).
  // Stage schedule (each stage >=1 closed barrier after its region's last
  // read; B-h0 last read ph1, B-h1 ph2, A ph3 within each K-tile):
  //   ph1: A(b)h0 [+lgkmcnt(8) pacing]   ph2: A(b)h1, mid: B(a+2)h0
  //   ph3': pre: B(a+2)h1; vmcnt(4)      ph5: A(a+2)h0 [+pacing]
  //   ph6: A(a+2)h1, mid: B(a+3)h0       ph7': pre: B(a+3)h1; vmcnt(4)
  // Ledger: ph3' vmcnt(4) -> outstanding = B(a+2)h0+h1 -> A(b),B(b)
  // certified for ph5-8. ph7' vmcnt(4) -> outstanding = B(a+3) ->
  // A(a+2),B(a+2) certified for next ph1-4. Never 0 mid-loop.
  auto iter = [&](int a, bool f) {
    const int b = a + 1;
    // ph1
    rdA(0, 0); rdB(0, 0, bLo);
    stageA(b, 0);
    asm volatile("s_waitcnt lgkmcnt(8)" ::: "memory");  // pacing (m201)
    BAR(); mma(0, 0, bLo); BAR();
    // ph2
    rdB(0, 1, bHi);
    stageA(b, 1);
    BAR();
    mma(0, 1, bHi);
    if (f) stageB(a + 2, 0);   // mid-cluster: B-h0 last read ph1 (closed)
    BAR();
    // ph3' (merged)
    rdA(0, 1);
    if (f) stageB(a + 2, 1);   // pre-bar: B-h1 last read ph2 (closed)
    BAR();
    mma(1, 1, bHi);
    mma(1, 0, bLo);
    if (f) { asm volatile("s_waitcnt vmcnt(4)" ::: "memory"); }
    else   { asm volatile("s_waitcnt vmcnt(0)" ::: "memory"); }
    BAR();
    // ph5
    rdA(1, 0); rdB(1, 0, bLo);
    if (f) stageA(a + 2, 0);
    asm volatile("s_waitcnt lgkmcnt(8)" ::: "memory");  // pacing
    BAR(); mma(0, 0, bLo); BAR();
    // ph6
    rdB(1, 1, bHi);
    if (f) stageA(a + 2, 1);
    BAR();
    mma(0, 1, bHi);
    if (f) stageB(a + 3, 0);   // mid-cluster
    BAR();
    // ph7' (merged)
    rdA(1, 1);
    if (f) stageB(a + 3, 1);   // pre-bar
    BAR();
    mma(1, 1, bHi);
    mma(1, 0, bLo);
    if (f) { asm volatile("s_waitcnt vmcnt(4)" ::: "memory"); }
    BAR();
  };

  // prologue: B(0), A(0), B(1) = 12 loads; vmcnt(4) leaves B(1) in flight.
  stageB(0, 0); stageB(0, 1);
  stageA(0, 0); stageA(0, 1);
  stageB(1, 0); stageB(1, 1);
  asm volatile("s_waitcnt vmcnt(4)" ::: "memory");
  BAR();

  for (int it = 0; it < NIT - 1; ++it) iter(2 * it, true);
  iter(NT - 2, false);

  // epilogue: C/D layout col=lane&15, row=(lane>>4)*4+reg (m89/m91)
  const int r0 = (lane >> 4) * 4;
#pragma unroll
  for (int m = 0; m < 8; ++m) {
#pragma unroll
    for (int r = 0; r < 4; ++r) {
      size_t row = (size_t)(rowBase + wr * 128 + m * 16 + r0 + r);
      float* po = out + row * N_DIM + colBase + wc * 64 + fr;
#pragma unroll
      for (int n = 0; n < 4; ++n)
        po[n * 16] = acc[m][n][r] + bias_v[n];
    }
  }
}

extern "C" void kernel_launch(void* const* d_in, const int* in_sizes, int n_in,
                              void* d_out, int out_size, void* d_ws, size_t ws_size,
                              hipStream_t stream) {
  const float* x = (const float*)d_in[0];   // [8192][4096]
  const float* w = (const float*)d_in[1];   // [11008][4096]
  const float* sc = (const float*)d_in[2];  // [11008]
  const float* bi = (const float*)d_in[3];  // [11008]
  float* out = (float*)d_out;

  const size_t xe = (size_t)M_DIM * K_DIM;
  const size_t we = (size_t)N_DIM * K_DIM;
  unsigned short* xb = (unsigned short*)d_ws;
  unsigned short* wb = xb + xe;

  cvt_x_kernel<<<(unsigned)(xe / 8 / 256), 256, 0, stream>>>(x, xb);
  cvt_w_kernel<<<(unsigned)(we / 8 / 256), 256, 0, stream>>>(w, sc, wb);
  gemm_kernel<<<NWG, 512, 0, stream>>>(xb, wb, bi, out);
}